// Round 1
// baseline (221.041 us; speedup 1.0000x reference)
//
#include <hip/hip_runtime.h>

// NCC loss, window 9, zero-padded separable box sums.
// Shapes: (2,1,160,160,160) f32. Output: scalar f32.
//
// 3-pass separable plan per batch volume (batches sequential to halve ws):
//   pass1: W-axis 9-tap sum of the 5 product channels (LDS-staged rows)
//   pass2: H-axis sliding-window sum (coalesced, lanes along w)
//   pass3: D-axis sliding-window sum fused with cc formula + reduction
// ws layout: A[5*VOL] | B[5*VOL] | partials[1600]  (~156 MiB)

#define DIM 160
#define HW  (160 * 160)        // 25600
#define VOL (160 * 160 * 160)  // 4096000
#define NBATCH 2
#define SEG 20                 // outputs per thread in sliding passes
#define SEGS (DIM / SEG)       // 8

__global__ __launch_bounds__(256) void pass1_wsum(const float* __restrict__ I,
                                                  const float* __restrict__ J,
                                                  float* __restrict__ A) {
    __shared__ float sI[32][161];
    __shared__ float sJ[32][161];
    const int tid = threadIdx.x;
    const int r0 = blockIdx.x * 32;  // first (d*160+h) row of this block

    for (int i = tid; i < 32 * DIM; i += 256) {
        int r = i / DIM, w = i - r * DIM;
        int g = (r0 + r) * DIM + w;
        sI[r][w] = I[g];
        sJ[r][w] = J[g];
    }
    __syncthreads();

    for (int i = tid; i < 32 * DIM; i += 256) {
        int r = i / DIM, w = i - r * DIM;
        float s0 = 0.f, s1 = 0.f, s2 = 0.f, s3 = 0.f, s4 = 0.f;
#pragma unroll
        for (int k = -4; k <= 4; ++k) {
            int ww = w + k;
            if (ww >= 0 && ww < DIM) {
                float a = sI[r][ww], b = sJ[r][ww];
                s0 += a;
                s1 += b;
                s2 += a * a;
                s3 += b * b;
                s4 += a * b;
            }
        }
        int g = (r0 + r) * DIM + w;
        A[0 * VOL + g] = s0;
        A[1 * VOL + g] = s1;
        A[2 * VOL + g] = s2;
        A[3 * VOL + g] = s3;
        A[4 * VOL + g] = s4;
    }
}

__global__ __launch_bounds__(256) void pass2_hsum(const float* __restrict__ A,
                                                  float* __restrict__ B) {
    int t = blockIdx.x * 256 + threadIdx.x;  // < 160*SEGS*160 = 204800
    int w = t % DIM;
    int rest = t / DIM;
    int seg = rest % SEGS;
    int d = rest / SEGS;
    int h0 = seg * SEG;
    const int base = d * HW + w;

    float s0 = 0.f, s1 = 0.f, s2 = 0.f, s3 = 0.f, s4 = 0.f;
#pragma unroll
    for (int k = -4; k <= 4; ++k) {
        int hh = h0 + k;
        if (hh >= 0) {  // hh <= 144 < 160 always
            int idx = base + hh * DIM;
            s0 += A[0 * VOL + idx];
            s1 += A[1 * VOL + idx];
            s2 += A[2 * VOL + idx];
            s3 += A[3 * VOL + idx];
            s4 += A[4 * VOL + idx];
        }
    }
    for (int h = h0; h < h0 + SEG; ++h) {
        int idx = base + h * DIM;
        B[0 * VOL + idx] = s0;
        B[1 * VOL + idx] = s1;
        B[2 * VOL + idx] = s2;
        B[3 * VOL + idx] = s3;
        B[4 * VOL + idx] = s4;
        int lead = h + 5, trail = h - 4;
        if (lead < DIM) {
            int li = base + lead * DIM;
            s0 += A[0 * VOL + li];
            s1 += A[1 * VOL + li];
            s2 += A[2 * VOL + li];
            s3 += A[3 * VOL + li];
            s4 += A[4 * VOL + li];
        }
        if (trail >= 0) {
            int ti = base + trail * DIM;
            s0 -= A[0 * VOL + ti];
            s1 -= A[1 * VOL + ti];
            s2 -= A[2 * VOL + ti];
            s3 -= A[3 * VOL + ti];
            s4 -= A[4 * VOL + ti];
        }
    }
}

__global__ __launch_bounds__(256) void pass3_dsum_final(const float* __restrict__ B,
                                                        float* __restrict__ partial) {
    int t = blockIdx.x * 256 + threadIdx.x;  // < SEGS*160*160 = 204800
    int w = t % DIM;
    int rest = t / DIM;
    int h = rest % DIM;
    int seg = rest / DIM;  // 0..7
    int d0 = seg * SEG;
    const int base = h * DIM + w;

    float s0 = 0.f, s1 = 0.f, s2 = 0.f, s3 = 0.f, s4 = 0.f;
#pragma unroll
    for (int k = -4; k <= 4; ++k) {
        int dd = d0 + k;
        if (dd >= 0) {
            int idx = base + dd * HW;
            s0 += B[0 * VOL + idx];
            s1 += B[1 * VOL + idx];
            s2 += B[2 * VOL + idx];
            s3 += B[3 * VOL + idx];
            s4 += B[4 * VOL + idx];
        }
    }

    const float wsz = 729.0f;
    const float inv_wsz = 1.0f / 729.0f;
    float acc = 0.f;
    for (int d = d0; d < d0 + SEG; ++d) {
        float uI = s0 * inv_wsz;
        float uJ = s1 * inv_wsz;
        float cross = s4 - uJ * s0 - uI * s1 + uI * uJ * wsz;
        float Ivar = s2 - 2.0f * uI * s0 + uI * uI * wsz;
        float Jvar = s3 - 2.0f * uJ * s1 + uJ * uJ * wsz;
        float cc = cross * cross / (Ivar * Jvar + 1e-5f);
        cc = fminf(fmaxf(cc, 0.0f), 1.0f);
        acc += cc;

        int lead = d + 5, trail = d - 4;
        if (lead < DIM) {
            int li = base + lead * HW;
            s0 += B[0 * VOL + li];
            s1 += B[1 * VOL + li];
            s2 += B[2 * VOL + li];
            s3 += B[3 * VOL + li];
            s4 += B[4 * VOL + li];
        }
        if (trail >= 0) {
            int ti = base + trail * HW;
            s0 -= B[0 * VOL + ti];
            s1 -= B[1 * VOL + ti];
            s2 -= B[2 * VOL + ti];
            s3 -= B[3 * VOL + ti];
            s4 -= B[4 * VOL + ti];
        }
    }

    // block reduction: wave shuffle then LDS across the 4 waves
#pragma unroll
    for (int off = 32; off > 0; off >>= 1) acc += __shfl_down(acc, off);
    __shared__ float ws4[4];
    if ((threadIdx.x & 63) == 0) ws4[threadIdx.x >> 6] = acc;
    __syncthreads();
    if (threadIdx.x == 0)
        partial[blockIdx.x] = ws4[0] + ws4[1] + ws4[2] + ws4[3];
}

__global__ __launch_bounds__(256) void final_reduce(const float* __restrict__ partial,
                                                    int n, float* __restrict__ out) {
    float a = 0.f;
    for (int i = threadIdx.x; i < n; i += 256) a += partial[i];
#pragma unroll
    for (int off = 32; off > 0; off >>= 1) a += __shfl_down(a, off);
    __shared__ float ws4[4];
    if ((threadIdx.x & 63) == 0) ws4[threadIdx.x >> 6] = a;
    __syncthreads();
    if (threadIdx.x == 0)
        out[0] = 1.0f - (ws4[0] + ws4[1] + ws4[2] + ws4[3]) *
                            (1.0f / (float)(NBATCH * VOL));
}

extern "C" void kernel_launch(void* const* d_in, const int* in_sizes, int n_in,
                              void* d_out, int out_size, void* d_ws, size_t ws_size,
                              hipStream_t stream) {
    const float* I = (const float*)d_in[0];
    const float* J = (const float*)d_in[1];
    float* out = (float*)d_out;

    float* A = (float*)d_ws;
    float* B = A + 5 * (size_t)VOL;
    float* partial = B + 5 * (size_t)VOL;
    // required ws: (10*VOL + 2*800) * 4 bytes ~= 156.3 MiB

    for (int n = 0; n < NBATCH; ++n) {
        pass1_wsum<<<HW / 32, 256, 0, stream>>>(I + (size_t)n * VOL,
                                                J + (size_t)n * VOL, A);
        pass2_hsum<<<(DIM * SEGS * DIM) / 256, 256, 0, stream>>>(A, B);
        pass3_dsum_final<<<(SEGS * DIM * DIM) / 256, 256, 0, stream>>>(
            B, partial + n * 800);
    }
    final_reduce<<<1, 256, 0, stream>>>(partial, NBATCH * 800, out);
}

// Round 2
// 121.569 us; speedup vs baseline: 1.8182x; 1.8182x over previous
//
#include <hip/hip_runtime.h>

// NCC loss, window 9, zero-padded separable box sums.
// Shapes: (2,1,160,160,160) f32. Output: scalar f32.
//
// 2-kernel plan, both batches in one grid per kernel:
//   K1: per d-slice fused W+H 2D 9x9 box sum of the 5 product channels
//       (LDS-staged 40x40 halo tile -> wsum LDS -> global A planes)
//   K2: D-axis sliding-window sum fused with cc formula + block reduction
// ws layout: A[2][5][VOL] | partials[1600]  (~156.3 MiB)

#define DIM 160
#define HW  (160 * 160)        // 25600
#define VOL (160 * 160 * 160)  // 4096000
#define NBATCH 2
#define TIL 32                 // K1 output tile (h,w)
#define STG 40                 // staged tile with +-4 halo
#define SEG 20                 // outputs per thread in K2 d-slide
#define SEGS (DIM / SEG)       // 8

__global__ __launch_bounds__(256) void k1_boxsum2d(const float* __restrict__ I,
                                                   const float* __restrict__ J,
                                                   float* __restrict__ A) {
    __shared__ float sI[STG][STG];           // 6.4 KB
    __shared__ float sJ[STG][STG];           // 6.4 KB
    __shared__ float wsum[5][STG][STG];      // 32 KB (stride 40: 2-way banks, free)

    const int tid = threadIdx.x;
    const int tx = blockIdx.x % 5, ty = blockIdx.x / 5;
    const int d = blockIdx.y;
    const int batch = blockIdx.z;
    const int h0 = ty * TIL, w0 = tx * TIL;
    const float* Ib = I + (size_t)batch * VOL + (size_t)d * HW;
    const float* Jb = J + (size_t)batch * VOL + (size_t)d * HW;

    // ---- stage 40x40 (zero halo), 10 float4 per row, 400 tasks per input ----
    for (int t = tid; t < 800; t += 256) {
        int which = t >= 400;
        int rem = which ? t - 400 : t;
        int r = rem / 10, q = rem - r * 10;
        int gh = h0 - 4 + r;
        int gw = w0 - 4 + 4 * q;
        float4 v = make_float4(0.f, 0.f, 0.f, 0.f);
        if (gh >= 0 && gh < DIM) {
            const float* p = (which ? Jb : Ib) + gh * DIM;
            if (gw >= 0 && gw + 3 < DIM) {
                v = *(const float4*)(p + gw);
            } else {
                if (gw + 0 >= 0 && gw + 0 < DIM) v.x = p[gw + 0];
                if (gw + 1 >= 0 && gw + 1 < DIM) v.y = p[gw + 1];
                if (gw + 2 >= 0 && gw + 2 < DIM) v.z = p[gw + 2];
                if (gw + 3 >= 0 && gw + 3 < DIM) v.w = p[gw + 3];
            }
        }
        float* dst = (which ? &sJ[0][0] : &sI[0][0]) + r * STG + 4 * q;
        *(float4*)dst = v;
    }
    __syncthreads();

    // ---- W-stage: 9-tap sum along w for all 40 rows, interior 32 cols ----
    // task (r, g): row r, output cols 4g..4g+3 (tile w coords)
    for (int t = tid; t < 320; t += 256) {
        int r = t >> 3, g = t & 7;
        const float* rI = &sI[r][0];
        const float* rJ = &sJ[r][0];
        float a[12], b[12];
        *(float4*)&a[0] = *(const float4*)(rI + 4 * g);
        *(float4*)&a[4] = *(const float4*)(rI + 4 * g + 4);
        *(float4*)&a[8] = *(const float4*)(rI + 4 * g + 8);
        *(float4*)&b[0] = *(const float4*)(rJ + 4 * g);
        *(float4*)&b[4] = *(const float4*)(rJ + 4 * g + 4);
        *(float4*)&b[8] = *(const float4*)(rJ + 4 * g + 8);

        float o0[4], o1[4], o2[4], o3[4], o4[4];
        float s0 = 0.f, s1 = 0.f, s2 = 0.f, s3 = 0.f, s4 = 0.f;
#pragma unroll
        for (int k = 0; k < 9; ++k) {
            float x = a[k], y = b[k];
            s0 += x; s1 += y; s2 += x * x; s3 += y * y; s4 += x * y;
        }
        o0[0] = s0; o1[0] = s1; o2[0] = s2; o3[0] = s3; o4[0] = s4;
#pragma unroll
        for (int j = 1; j < 4; ++j) {
            float xl = a[j + 8], yl = b[j + 8], xt = a[j - 1], yt = b[j - 1];
            s0 += xl - xt;
            s1 += yl - yt;
            s2 += xl * xl - xt * xt;
            s3 += yl * yl - yt * yt;
            s4 += xl * yl - xt * yt;
            o0[j] = s0; o1[j] = s1; o2[j] = s2; o3[j] = s3; o4[j] = s4;
        }
        float* wp = &wsum[0][0][0] + r * STG + 4 * g;
        *(float4*)(wp + 0 * STG * STG) = *(float4*)o0;
        *(float4*)(wp + 1 * STG * STG) = *(float4*)o1;
        *(float4*)(wp + 2 * STG * STG) = *(float4*)o2;
        *(float4*)(wp + 3 * STG * STG) = *(float4*)o3;
        *(float4*)(wp + 4 * STG * STG) = *(float4*)o4;
    }
    __syncthreads();

    // ---- H-stage: 9-tap sliding sum along h, write c[5] planes to A ----
    {
        const int w = tid & 31;        // tile w
        const int hg = tid >> 5;       // 0..7, 4 h-outputs each
        const float* wp = &wsum[0][0][0];
        float s0 = 0.f, s1 = 0.f, s2 = 0.f, s3 = 0.f, s4 = 0.f;
#pragma unroll
        for (int k = 0; k < 9; ++k) {
            int rr = 4 * hg + k;       // wsum row = tile h + 4 shifted window
            int idx = rr * STG + w;
            s0 += wp[0 * STG * STG + idx];
            s1 += wp[1 * STG * STG + idx];
            s2 += wp[2 * STG * STG + idx];
            s3 += wp[3 * STG * STG + idx];
            s4 += wp[4 * STG * STG + idx];
        }
        const size_t obase = (size_t)batch * 5 * VOL + (size_t)d * HW;
#pragma unroll
        for (int j = 0; j < 4; ++j) {
            int gh = h0 + 4 * hg + j;
            int gw = w0 + w;
            size_t o = obase + (size_t)gh * DIM + gw;
            A[o + 0 * (size_t)VOL] = s0;
            A[o + 1 * (size_t)VOL] = s1;
            A[o + 2 * (size_t)VOL] = s2;
            A[o + 3 * (size_t)VOL] = s3;
            A[o + 4 * (size_t)VOL] = s4;
            if (j < 3) {
                int ra = (4 * hg + j + 9) * STG + w;
                int rs = (4 * hg + j) * STG + w;
                s0 += wp[0 * STG * STG + ra] - wp[0 * STG * STG + rs];
                s1 += wp[1 * STG * STG + ra] - wp[1 * STG * STG + rs];
                s2 += wp[2 * STG * STG + ra] - wp[2 * STG * STG + rs];
                s3 += wp[3 * STG * STG + ra] - wp[3 * STG * STG + rs];
                s4 += wp[4 * STG * STG + ra] - wp[4 * STG * STG + rs];
            }
        }
    }
}

__global__ __launch_bounds__(256) void k2_dsum_final(const float* __restrict__ Aall,
                                                     float* __restrict__ partial) {
    const int batch = blockIdx.y;
    const float* B = Aall + (size_t)batch * 5 * VOL;
    int t = blockIdx.x * 256 + threadIdx.x;  // < SEGS*160*160 = 204800
    int w = t % DIM;
    int rest = t / DIM;
    int h = rest % DIM;
    int seg = rest / DIM;  // 0..7
    int d0 = seg * SEG;
    const int base = h * DIM + w;

    float s0 = 0.f, s1 = 0.f, s2 = 0.f, s3 = 0.f, s4 = 0.f;
#pragma unroll
    for (int k = -4; k <= 4; ++k) {
        int dd = d0 + k;
        if (dd >= 0) {
            int idx = base + dd * HW;
            s0 += B[0 * VOL + idx];
            s1 += B[1 * VOL + idx];
            s2 += B[2 * VOL + idx];
            s3 += B[3 * VOL + idx];
            s4 += B[4 * VOL + idx];
        }
    }

    const float wsz = 729.0f;
    const float inv_wsz = 1.0f / 729.0f;
    float acc = 0.f;
    for (int d = d0; d < d0 + SEG; ++d) {
        float uI = s0 * inv_wsz;
        float uJ = s1 * inv_wsz;
        float cross = s4 - uJ * s0 - uI * s1 + uI * uJ * wsz;
        float Ivar = s2 - 2.0f * uI * s0 + uI * uI * wsz;
        float Jvar = s3 - 2.0f * uJ * s1 + uJ * uJ * wsz;
        float cc = cross * cross / (Ivar * Jvar + 1e-5f);
        cc = fminf(fmaxf(cc, 0.0f), 1.0f);
        acc += cc;

        int lead = d + 5, trail = d - 4;
        if (lead < DIM) {
            int li = base + lead * HW;
            s0 += B[0 * VOL + li];
            s1 += B[1 * VOL + li];
            s2 += B[2 * VOL + li];
            s3 += B[3 * VOL + li];
            s4 += B[4 * VOL + li];
        }
        if (trail >= 0) {
            int ti = base + trail * HW;
            s0 -= B[0 * VOL + ti];
            s1 -= B[1 * VOL + ti];
            s2 -= B[2 * VOL + ti];
            s3 -= B[3 * VOL + ti];
            s4 -= B[4 * VOL + ti];
        }
    }

#pragma unroll
    for (int off = 32; off > 0; off >>= 1) acc += __shfl_down(acc, off);
    __shared__ float ws4[4];
    if ((threadIdx.x & 63) == 0) ws4[threadIdx.x >> 6] = acc;
    __syncthreads();
    if (threadIdx.x == 0)
        partial[batch * 800 + blockIdx.x] = ws4[0] + ws4[1] + ws4[2] + ws4[3];
}

__global__ __launch_bounds__(256) void final_reduce(const float* __restrict__ partial,
                                                    int n, float* __restrict__ out) {
    float a = 0.f;
    for (int i = threadIdx.x; i < n; i += 256) a += partial[i];
#pragma unroll
    for (int off = 32; off > 0; off >>= 1) a += __shfl_down(a, off);
    __shared__ float ws4[4];
    if ((threadIdx.x & 63) == 0) ws4[threadIdx.x >> 6] = a;
    __syncthreads();
    if (threadIdx.x == 0)
        out[0] = 1.0f - (ws4[0] + ws4[1] + ws4[2] + ws4[3]) *
                            (1.0f / (float)(NBATCH * VOL));
}

extern "C" void kernel_launch(void* const* d_in, const int* in_sizes, int n_in,
                              void* d_out, int out_size, void* d_ws, size_t ws_size,
                              hipStream_t stream) {
    const float* I = (const float*)d_in[0];
    const float* J = (const float*)d_in[1];
    float* out = (float*)d_out;

    float* A = (float*)d_ws;                       // [2][5][VOL]
    float* partial = A + (size_t)NBATCH * 5 * VOL; // [1600]

    dim3 g1(25, DIM, NBATCH);
    k1_boxsum2d<<<g1, 256, 0, stream>>>(I, J, A);
    dim3 g2(800, NBATCH);
    k2_dsum_final<<<g2, 256, 0, stream>>>(A, partial);
    final_reduce<<<1, 256, 0, stream>>>(partial, NBATCH * 800, out);
}

// Round 3
// 91.529 us; speedup vs baseline: 2.4150x; 1.3282x over previous
//
#include <hip/hip_runtime.h>
#include <hip/hip_fp16.h>

// NCC loss, window 9, zero-padded separable box sums.
// Shapes: (2,1,160,160,160) f32. Output: scalar f32.
//
// K1: per d-slice fused W+H 2D 9x9 box sum of 5 product channels,
//     intermediate A stored as fp16 (sums <= 81, rel err ~5e-4 -> final
//     loss error ~1e-6, threshold 1.9e-2).
// K2: D-axis sliding-window sum (half2 loads) fused with cc + reduction.
// ws layout: A[2][5][VOL] as half (82 MB) | partials[800] f32

#define DIM 160
#define HW  (160 * 160)
#define VOL (160 * 160 * 160)
#define VOLH2 (VOL / 2)
#define HWH2 (HW / 2)
#define NBATCH 2
#define TIL 32
#define STG 40
#define WPAD 36                // wsum row stride (keeps 16B alignment)
#define SEG 20
#define SEGS (DIM / SEG)

__global__ __launch_bounds__(256) void k1_boxsum2d(const float* __restrict__ I,
                                                   const float* __restrict__ J,
                                                   __half2* __restrict__ A) {
    __shared__ float sI[STG][STG];             // 6.4 KB
    __shared__ float sJ[STG][STG];             // 6.4 KB
    __shared__ float wsum[5][STG][WPAD];       // 28.8 KB

    const int tid = threadIdx.x;
    const int tx = blockIdx.x % 5, ty = blockIdx.x / 5;
    const int d = blockIdx.y;
    const int batch = blockIdx.z;
    const int h0 = ty * TIL, w0 = tx * TIL;
    const float* Ib = I + (size_t)batch * VOL + (size_t)d * HW;
    const float* Jb = J + (size_t)batch * VOL + (size_t)d * HW;

    // ---- stage 40x40 (zero halo), float4 loads ----
    for (int t = tid; t < 800; t += 256) {
        int which = t >= 400;
        int rem = which ? t - 400 : t;
        int r = rem / 10, q = rem - r * 10;
        int gh = h0 - 4 + r;
        int gw = w0 - 4 + 4 * q;
        float4 v = make_float4(0.f, 0.f, 0.f, 0.f);
        if (gh >= 0 && gh < DIM) {
            const float* p = (which ? Jb : Ib) + gh * DIM;
            if (gw >= 0 && gw + 3 < DIM) {
                v = *(const float4*)(p + gw);
            } else {
                if (gw + 0 >= 0 && gw + 0 < DIM) v.x = p[gw + 0];
                if (gw + 1 >= 0 && gw + 1 < DIM) v.y = p[gw + 1];
                if (gw + 2 >= 0 && gw + 2 < DIM) v.z = p[gw + 2];
                if (gw + 3 >= 0 && gw + 3 < DIM) v.w = p[gw + 3];
            }
        }
        float* dst = (which ? &sJ[0][0] : &sI[0][0]) + r * STG + 4 * q;
        *(float4*)dst = v;
    }
    __syncthreads();

    // ---- W-stage: 9-tap sliding sum along w, 40 rows x 32 interior cols ----
    for (int t = tid; t < 320; t += 256) {
        int r = t >> 3, g = t & 7;
        const float* rI = &sI[r][0];
        const float* rJ = &sJ[r][0];
        float a[12], b[12];
        *(float4*)&a[0] = *(const float4*)(rI + 4 * g);
        *(float4*)&a[4] = *(const float4*)(rI + 4 * g + 4);
        *(float4*)&a[8] = *(const float4*)(rI + 4 * g + 8);
        *(float4*)&b[0] = *(const float4*)(rJ + 4 * g);
        *(float4*)&b[4] = *(const float4*)(rJ + 4 * g + 4);
        *(float4*)&b[8] = *(const float4*)(rJ + 4 * g + 8);

        float o0[4], o1[4], o2[4], o3[4], o4[4];
        float s0 = 0.f, s1 = 0.f, s2 = 0.f, s3 = 0.f, s4 = 0.f;
#pragma unroll
        for (int k = 0; k < 9; ++k) {
            float x = a[k], y = b[k];
            s0 += x; s1 += y; s2 += x * x; s3 += y * y; s4 += x * y;
        }
        o0[0] = s0; o1[0] = s1; o2[0] = s2; o3[0] = s3; o4[0] = s4;
#pragma unroll
        for (int j = 1; j < 4; ++j) {
            float xl = a[j + 8], yl = b[j + 8], xt = a[j - 1], yt = b[j - 1];
            s0 += xl - xt;
            s1 += yl - yt;
            s2 += xl * xl - xt * xt;
            s3 += yl * yl - yt * yt;
            s4 += xl * yl - xt * yt;
            o0[j] = s0; o1[j] = s1; o2[j] = s2; o3[j] = s3; o4[j] = s4;
        }
        float* wp = &wsum[0][0][0] + r * WPAD + 4 * g;
        *(float4*)(wp + 0 * STG * WPAD) = *(float4*)o0;
        *(float4*)(wp + 1 * STG * WPAD) = *(float4*)o1;
        *(float4*)(wp + 2 * STG * WPAD) = *(float4*)o2;
        *(float4*)(wp + 3 * STG * WPAD) = *(float4*)o3;
        *(float4*)(wp + 4 * STG * WPAD) = *(float4*)o4;
    }
    __syncthreads();

    // ---- H-stage: 2h x 2w per thread, 9-tap + 1 slide, store half2 ----
    {
        const int wq = tid & 15;       // w-pair
        const int hq = tid >> 4;       // h-pair (0..15)
        const int hsub = 2 * hq;
        const size_t obase = (size_t)batch * 5 * VOLH2 + (size_t)d * HWH2 +
                             (size_t)(h0 + hsub) * (DIM / 2) + (size_t)(tx * 16 + wq);
#pragma unroll
        for (int ch = 0; ch < 5; ++ch) {
            const float* wp = &wsum[ch][0][0] + 2 * wq;
            float rx[10], ry[10];
#pragma unroll
            for (int k = 0; k < 10; ++k) {
                float2 v = *(const float2*)(wp + (hsub + k) * WPAD);
                rx[k] = v.x; ry[k] = v.y;
            }
            float sx = 0.f, sy = 0.f;
#pragma unroll
            for (int k = 0; k < 9; ++k) { sx += rx[k]; sy += ry[k]; }
            float tx2 = sx - rx[0] + rx[9];
            float ty2 = sy - ry[0] + ry[9];
            A[obase + (size_t)ch * VOLH2]            = __floats2half2_rn(sx, sy);
            A[obase + (size_t)ch * VOLH2 + DIM / 2]  = __floats2half2_rn(tx2, ty2);
        }
    }
}

__global__ __launch_bounds__(256) void k2_dsum_final(const __half2* __restrict__ Aall,
                                                     float* __restrict__ partial) {
    const int batch = blockIdx.y;
    const __half2* B = Aall + (size_t)batch * 5 * VOLH2;
    int t = blockIdx.x * 256 + threadIdx.x;  // < 80*160*8 = 102400
    int wq = t % (DIM / 2);
    int rest = t / (DIM / 2);
    int h = rest % DIM;
    int seg = rest / DIM;                    // 0..7
    int d0 = seg * SEG;
    const int base = h * (DIM / 2) + wq;

    float2 s0 = {0.f, 0.f}, s1 = {0.f, 0.f}, s2 = {0.f, 0.f},
           s3 = {0.f, 0.f}, s4 = {0.f, 0.f};
#pragma unroll
    for (int k = -4; k <= 4; ++k) {
        int dd = d0 + k;
        if (dd >= 0) {
            int idx = base + dd * HWH2;
            float2 v;
            v = __half22float2(B[0 * VOLH2 + idx]); s0.x += v.x; s0.y += v.y;
            v = __half22float2(B[1 * VOLH2 + idx]); s1.x += v.x; s1.y += v.y;
            v = __half22float2(B[2 * VOLH2 + idx]); s2.x += v.x; s2.y += v.y;
            v = __half22float2(B[3 * VOLH2 + idx]); s3.x += v.x; s3.y += v.y;
            v = __half22float2(B[4 * VOLH2 + idx]); s4.x += v.x; s4.y += v.y;
        }
    }

    const float inv_wsz = 1.0f / 729.0f;
    float acc = 0.f;
    for (int d = d0; d < d0 + SEG; ++d) {
        {
            float cross = s4.x - s0.x * s1.x * inv_wsz;
            float Ivar  = s2.x - s0.x * s0.x * inv_wsz;
            float Jvar  = s3.x - s1.x * s1.x * inv_wsz;
            float cc = cross * cross * __builtin_amdgcn_rcpf(Ivar * Jvar + 1e-5f);
            acc += fminf(fmaxf(cc, 0.0f), 1.0f);
        }
        {
            float cross = s4.y - s0.y * s1.y * inv_wsz;
            float Ivar  = s2.y - s0.y * s0.y * inv_wsz;
            float Jvar  = s3.y - s1.y * s1.y * inv_wsz;
            float cc = cross * cross * __builtin_amdgcn_rcpf(Ivar * Jvar + 1e-5f);
            acc += fminf(fmaxf(cc, 0.0f), 1.0f);
        }
        int lead = d + 5, trail = d - 4;
        if (lead < DIM) {
            int li = base + lead * HWH2;
            float2 v;
            v = __half22float2(B[0 * VOLH2 + li]); s0.x += v.x; s0.y += v.y;
            v = __half22float2(B[1 * VOLH2 + li]); s1.x += v.x; s1.y += v.y;
            v = __half22float2(B[2 * VOLH2 + li]); s2.x += v.x; s2.y += v.y;
            v = __half22float2(B[3 * VOLH2 + li]); s3.x += v.x; s3.y += v.y;
            v = __half22float2(B[4 * VOLH2 + li]); s4.x += v.x; s4.y += v.y;
        }
        if (trail >= 0) {
            int ti = base + trail * HWH2;
            float2 v;
            v = __half22float2(B[0 * VOLH2 + ti]); s0.x -= v.x; s0.y -= v.y;
            v = __half22float2(B[1 * VOLH2 + ti]); s1.x -= v.x; s1.y -= v.y;
            v = __half22float2(B[2 * VOLH2 + ti]); s2.x -= v.x; s2.y -= v.y;
            v = __half22float2(B[3 * VOLH2 + ti]); s3.x -= v.x; s3.y -= v.y;
            v = __half22float2(B[4 * VOLH2 + ti]); s4.x -= v.x; s4.y -= v.y;
        }
    }

#pragma unroll
    for (int off = 32; off > 0; off >>= 1) acc += __shfl_down(acc, off);
    __shared__ float ws4[4];
    if ((threadIdx.x & 63) == 0) ws4[threadIdx.x >> 6] = acc;
    __syncthreads();
    if (threadIdx.x == 0)
        partial[batch * 400 + blockIdx.x] = ws4[0] + ws4[1] + ws4[2] + ws4[3];
}

__global__ __launch_bounds__(256) void final_reduce(const float* __restrict__ partial,
                                                    int n, float* __restrict__ out) {
    float a = 0.f;
    for (int i = threadIdx.x; i < n; i += 256) a += partial[i];
#pragma unroll
    for (int off = 32; off > 0; off >>= 1) a += __shfl_down(a, off);
    __shared__ float ws4[4];
    if ((threadIdx.x & 63) == 0) ws4[threadIdx.x >> 6] = a;
    __syncthreads();
    if (threadIdx.x == 0)
        out[0] = 1.0f - (ws4[0] + ws4[1] + ws4[2] + ws4[3]) *
                            (1.0f / (float)(NBATCH * VOL));
}

extern "C" void kernel_launch(void* const* d_in, const int* in_sizes, int n_in,
                              void* d_out, int out_size, void* d_ws, size_t ws_size,
                              hipStream_t stream) {
    const float* I = (const float*)d_in[0];
    const float* J = (const float*)d_in[1];
    float* out = (float*)d_out;

    __half2* A = (__half2*)d_ws;                        // [2][5][VOL] halves
    float* partial = (float*)((char*)d_ws +
                              (size_t)NBATCH * 5 * VOL * sizeof(__half)); // [800]

    dim3 g1(25, DIM, NBATCH);
    k1_boxsum2d<<<g1, 256, 0, stream>>>(I, J, A);
    dim3 g2(400, NBATCH);
    k2_dsum_final<<<g2, 256, 0, stream>>>(A, partial);
    final_reduce<<<1, 256, 0, stream>>>(partial, NBATCH * 400, out);
}